// Round 4
// baseline (266.465 us; speedup 1.0000x reference)
//
#include <hip/hip_runtime.h>
#include <hip/hip_bf16.h>

// pos[b][f][i][j] = row_embed[Z(i,j)][f],  Z = max(|32-j| + |32-i| - 1, 0)
// b=32, F=512, h=w=64. Output fp32, 256 MiB -> pure write-BW bound.
//
// R2 lesson: linear vs b-scattered write stream made no difference (265->257us);
// pe_kernel itself is <163us (absent from top-5; harness 1-GiB re-poison fills
// dominate the dispatch table). R3/R4: instruction-minimal form. One block per
// f: precompute the thread's 4 float4 values ONCE into registers (16 LDS reads,
// one barrier per block lifetime), then 128 pure register-sourced stores
// (1 addr add + 1 global_store_dwordx4 each) across the 32 batch copies.
// 512 blocks total -> no block churn. Nontemporal stores (256MB >> 32MB L2).
// R4 fix: __builtin_nontemporal_store needs a native ext_vector_type, not
// HIP's float4 struct.

#define NUM_POS_FEATS 512
#define H 64
#define W 64
#define B 32

typedef float vfloat4 __attribute__((ext_vector_type(4)));

__global__ __launch_bounds__(256) void pe_kernel(const float* __restrict__ row_embed,
                                                 float* __restrict__ out) {
    __shared__ float col[64];   // row_embed[z][f] for z in [0,64)

    const int f   = blockIdx.x;        // 0..511
    const int tid = threadIdx.x;

    if (tid < 64) {
        col[tid] = row_embed[tid * NUM_POS_FEATS + f];
    }
    __syncthreads();

    // Precompute this thread's 4 quads of the 64x64 image (1024 quads total).
    vfloat4 v[4];
#pragma unroll
    for (int k = 0; k < 4; ++k) {
        const int idx = k * 256 + tid;        // quad index 0..1023
        const int i   = idx >> 4;             // row
        const int j4  = (idx & 15) << 2;      // quad start column
        const int di  = abs(32 - i);

        int z0 = di + abs(32 - (j4 + 0)) - 1; z0 = z0 < 0 ? 0 : z0;
        int z1 = di + abs(32 - (j4 + 1)) - 1; z1 = z1 < 0 ? 0 : z1;
        int z2 = di + abs(32 - (j4 + 2)) - 1; z2 = z2 < 0 ? 0 : z2;
        int z3 = di + abs(32 - (j4 + 3)) - 1; z3 = z3 < 0 ? 0 : z3;
        v[k] = (vfloat4){col[z0], col[z1], col[z2], col[z3]};
    }

    // Stream stores: 32 batches x 4 quads, value from registers.
    vfloat4* obase = reinterpret_cast<vfloat4*>(out) + (size_t)f * (H * W / 4); // 1024 quads/image
    const size_t bstride = (size_t)NUM_POS_FEATS * (H * W / 4);                 // 524288 quads

    for (int b = 0; b < B; ++b) {
        vfloat4* o = obase + (size_t)b * bstride;
#pragma unroll
        for (int k = 0; k < 4; ++k) {
            __builtin_nontemporal_store(v[k], &o[k * 256 + tid]);
        }
    }
}

extern "C" void kernel_launch(void* const* d_in, const int* in_sizes, int n_in,
                              void* d_out, int out_size, void* d_ws, size_t ws_size,
                              hipStream_t stream) {
    // d_in[0] = x (32,3,64,64) fp32 — unused (shape only)
    // d_in[1] = row_embed (64,512) fp32
    const float* row_embed = (const float*)d_in[1];
    float* out = (float*)d_out;

    pe_kernel<<<NUM_POS_FEATS, 256, 0, stream>>>(row_embed, out);  // 512 blocks
}

// Round 5
// 257.123 us; speedup vs baseline: 1.0363x; 1.0363x over previous
//
#include <hip/hip_runtime.h>
#include <hip/hip_bf16.h>

// pos[b][f][i][j] = row_embed[Z(i,j)][f],  Z = max(|32-j| + |32-i| - 1, 0)
// b=32, F=512, h=w=64. Output fp32, 256 MiB -> pure write-BW bound.
//
// R1-R4 lessons: dur_us is fixed-harness-dominated (1-GiB re-poison fill
// ~168us + restore are inside the timed region; pe_kernel never shows in the
// top-5 dispatches). Scattered vs linear vs nt-stream store structures all
// land 257-266us. R5: final calibration — R2's winning regime (many blocks,
// plain dwordx4 stores) + register precompute + 4x gather/barrier
// amortization: each block handles 4 batch images of one feature.
// If this stays ~256-266us, the kernel is at the write floor and the rest is
// harness overhead -> roofline.

#define NUM_POS_FEATS 512
#define H 64
#define W 64
#define B 32

typedef float vfloat4 __attribute__((ext_vector_type(4)));

__global__ __launch_bounds__(256) void pe_kernel(const float* __restrict__ row_embed,
                                                 float* __restrict__ out) {
    __shared__ float col[64];   // row_embed[z][f] for z in [0,64)

    const int g   = blockIdx.x;        // 0..4095
    const int f   = g & (NUM_POS_FEATS - 1);
    const int b0  = (g >> 9) << 2;     // first of 4 batch images: 0,4,...,28
    const int tid = threadIdx.x;

    if (tid < 64) {
        col[tid] = row_embed[tid * NUM_POS_FEATS + f];
    }
    __syncthreads();

    // Precompute this thread's 4 quads of the 64x64 image into registers.
    vfloat4 v[4];
#pragma unroll
    for (int k = 0; k < 4; ++k) {
        const int idx = k * 256 + tid;        // quad index 0..1023
        const int i   = idx >> 4;             // row
        const int j4  = (idx & 15) << 2;      // quad start column
        const int di  = abs(32 - i);

        int z0 = di + abs(32 - (j4 + 0)) - 1; z0 = z0 < 0 ? 0 : z0;
        int z1 = di + abs(32 - (j4 + 1)) - 1; z1 = z1 < 0 ? 0 : z1;
        int z2 = di + abs(32 - (j4 + 2)) - 1; z2 = z2 < 0 ? 0 : z2;
        int z3 = di + abs(32 - (j4 + 3)) - 1; z3 = z3 < 0 ? 0 : z3;
        v[k] = (vfloat4){col[z0], col[z1], col[z2], col[z3]};
    }

    // Store to 4 batch copies, values from registers, plain dwordx4 stores.
    vfloat4* obase = reinterpret_cast<vfloat4*>(out) + (size_t)f * (H * W / 4);
    const size_t bstride = (size_t)NUM_POS_FEATS * (H * W / 4);   // quads per batch slice

#pragma unroll
    for (int q = 0; q < 4; ++q) {
        vfloat4* o = obase + (size_t)(b0 + q) * bstride;
#pragma unroll
        for (int k = 0; k < 4; ++k) {
            o[k * 256 + tid] = v[k];
        }
    }
}

extern "C" void kernel_launch(void* const* d_in, const int* in_sizes, int n_in,
                              void* d_out, int out_size, void* d_ws, size_t ws_size,
                              hipStream_t stream) {
    // d_in[0] = x (32,3,64,64) fp32 — unused (shape only)
    // d_in[1] = row_embed (64,512) fp32
    const float* row_embed = (const float*)d_in[1];
    float* out = (float*)d_out;

    const int grid = (B / 4) * NUM_POS_FEATS;   // 4096 blocks
    pe_kernel<<<grid, 256, 0, stream>>>(row_embed, out);
}